// Round 5
// baseline (320.657 us; speedup 1.0000x reference)
//
#include <hip/hip_runtime.h>

constexpr int NN = 50000;   // nodes
constexpr int NE = 800000;  // edges
constexpr int H  = 64;      // hidden
constexpr int NG = 64;      // graphs

constexpr int SCAN_B  = 1024;
constexpr int SCAN_NB = (NN + SCAN_B - 1) / SCAN_B;  // 49

// ---------------- zero scratch (replaces slow runtime memset) ----------------
__global__ void k_zero(int* __restrict__ degi, float* __restrict__ sums,
                       float* __restrict__ cnt) {
    int i = blockIdx.x * blockDim.x + threadIdx.x;
    const int total = NN + NG * H + NG;
    for (; i < total; i += gridDim.x * blockDim.x) {
        if (i < NN) degi[i] = 0;
        else if (i < NN + NG * H) sums[i - NN] = 0.0f;
        else cnt[i - NN - NG * H] = 0.0f;
    }
}

// ---------------- CSR build ----------------
__global__ void k_degi(const int* __restrict__ dst, int* __restrict__ degi) {
    int e = blockIdx.x * blockDim.x + threadIdx.x;
    if (e < NE) atomicAdd(&degi[dst[e]], 1);
}

// per-block local exclusive scan; bsum[b] = block total
__global__ void k_scanA(const int* __restrict__ degi, int* __restrict__ rowptr,
                        int* __restrict__ bsum) {
    int tid = threadIdx.x, b = blockIdx.x;
    int i = b * SCAN_B + tid;
    int d = (i < NN) ? degi[i] : 0;
    int lane = tid & 63, w = tid >> 6;
    int v = d;
    for (int off = 1; off < 64; off <<= 1) {
        int u = __shfl_up(v, off);
        if (lane >= off) v += u;
    }
    __shared__ int wt[16], wo[16];
    if (lane == 63) wt[w] = v;
    __syncthreads();
    if (tid == 0) {
        int a = 0;
        for (int k = 0; k < 16; ++k) { wo[k] = a; a += wt[k]; }
        bsum[b] = a;
    }
    __syncthreads();
    if (i < NN) rowptr[i] = v - d + wo[w];
}

// single wave: bsum -> exclusive offsets (in place)
__global__ void k_scanB(int* __restrict__ bsum) {
    int lane = threadIdx.x;
    int v = (lane < SCAN_NB) ? bsum[lane] : 0;
    int s = v;
    for (int off = 1; off < 64; off <<= 1) {
        int u = __shfl_up(s, off);
        if (lane >= off) s += u;
    }
    if (lane < SCAN_NB) bsum[lane] = s - v;
}

// add block offsets; fuse dinv
__global__ void k_scanC(const int* __restrict__ bsum, int* __restrict__ rowptr,
                        const int* __restrict__ degi, float* __restrict__ dinv) {
    int i = blockIdx.x * SCAN_B + threadIdx.x;
    if (i < NN) {
        rowptr[i] += bsum[blockIdx.x];
        dinv[i] = rsqrtf((float)(degi[i] + 1));  // +1 self-loop
    }
}

// fill: pos = atomicAdd(&rowptr[d],1). Afterwards rowptr[d] == old rowptr[d+1],
// so conv uses beg = rowptr[d-1] (or 0), end = rowptr[d].
__global__ void k_fill(const int* __restrict__ src, const int* __restrict__ dst,
                       int* __restrict__ rowptr, int* __restrict__ csr_src) {
    int e = blockIdx.x * blockDim.x + threadIdx.x;
    if (e >= NE) return;
    int s = src[e], d = dst[e];
    int pos = atomicAdd(&rowptr[d], 1);
    csr_src[pos] = s;
}

// ---------------- dense per-node GEMM: t = act(h) @ W ----------------
// block = 256 threads; each thread computes a 4-row x 4-channel micro-tile.
template <int K, bool RELU>
__global__ void k_gemm(const float* __restrict__ h, const float* __restrict__ W,
                       float* __restrict__ t) {
    __shared__ float4 Wl[K][16];
    int tid = threadIdx.x;
    {
        const float4* W4 = (const float4*)W;
        for (int i = tid; i < K * 16; i += 256) ((float4*)Wl)[i] = W4[i];
    }
    __syncthreads();
    int cg = tid & 15;   // channel group: channels 4*cg..4*cg+3
    int rg = tid >> 4;   // row group: 4 consecutive rows
    int row0 = blockIdx.x * 64 + rg * 4;

    float4 acc[4];
#pragma unroll
    for (int i = 0; i < 4; ++i) acc[i] = make_float4(0.f, 0.f, 0.f, 0.f);

    const float4* h4 = (const float4*)h;
#pragma unroll
    for (int k4 = 0; k4 < K / 4; ++k4) {
        float4 w0 = Wl[4 * k4 + 0][cg];
        float4 w1 = Wl[4 * k4 + 1][cg];
        float4 w2 = Wl[4 * k4 + 2][cg];
        float4 w3 = Wl[4 * k4 + 3][cg];
#pragma unroll
        for (int i = 0; i < 4; ++i) {
            int r = row0 + i;
            if (r >= NN) break;
            float4 hv = h4[(long long)r * (K / 4) + k4];
            if (RELU) {
                hv.x = fmaxf(hv.x, 0.f); hv.y = fmaxf(hv.y, 0.f);
                hv.z = fmaxf(hv.z, 0.f); hv.w = fmaxf(hv.w, 0.f);
            }
            acc[i].x = fmaf(hv.x, w0.x, acc[i].x);
            acc[i].y = fmaf(hv.x, w0.y, acc[i].y);
            acc[i].z = fmaf(hv.x, w0.z, acc[i].z);
            acc[i].w = fmaf(hv.x, w0.w, acc[i].w);
            acc[i].x = fmaf(hv.y, w1.x, acc[i].x);
            acc[i].y = fmaf(hv.y, w1.y, acc[i].y);
            acc[i].z = fmaf(hv.y, w1.z, acc[i].z);
            acc[i].w = fmaf(hv.y, w1.w, acc[i].w);
            acc[i].x = fmaf(hv.z, w2.x, acc[i].x);
            acc[i].y = fmaf(hv.z, w2.y, acc[i].y);
            acc[i].z = fmaf(hv.z, w2.z, acc[i].z);
            acc[i].w = fmaf(hv.z, w2.w, acc[i].w);
            acc[i].x = fmaf(hv.w, w3.x, acc[i].x);
            acc[i].y = fmaf(hv.w, w3.y, acc[i].y);
            acc[i].z = fmaf(hv.w, w3.z, acc[i].z);
            acc[i].w = fmaf(hv.w, w3.w, acc[i].w);
        }
    }
#pragma unroll
    for (int i = 0; i < 4; ++i) {
        int r = row0 + i;
        if (r < NN) *(float4*)(t + (long long)r * H + 4 * cg) = acc[i];
    }
}

// ---------------- pull conv ----------------
// out[d] = b + dinv[d]*( sum_s t[s]*dinv[s] + t[d]*dinv[d] )
// wave = 1 dst node; lane = (g = lane>>4 edge group, l = lane&15 float4 slot)
__global__ void k_conv(const float* __restrict__ t, const int* __restrict__ rowptr,
                       const int* __restrict__ csr_src, const float* __restrict__ dinv,
                       const float* __restrict__ b, float* __restrict__ out) {
    int wid = (blockIdx.x * blockDim.x + threadIdx.x) >> 6;
    int lane = threadIdx.x & 63;
    int l = lane & 15, g = lane >> 4;
    if (wid >= NN) return;
    float ax = 0.0f, ay = 0.0f, az = 0.0f, aw = 0.0f;
    int beg = (wid > 0) ? rowptr[wid - 1] : 0;
    int end = rowptr[wid];
    for (int base = beg; base < end; base += 64) {
        int k = base + lane;
        int s = 0; float w = 0.0f;
        if (k < end) { s = csr_src[k]; w = dinv[s]; }
        int n = end - base; if (n > 64) n = 64;
        int iters = (n + 3) >> 2;
        for (int j = 0; j < iters; ++j) {
            int idx = 4 * j + g;
            int ss = __shfl(s, idx);
            float ww = __shfl(w, idx);
            const float4 v = *(const float4*)(t + (long long)ss * H + 4 * l);
            ax = fmaf(v.x, ww, ax);
            ay = fmaf(v.y, ww, ay);
            az = fmaf(v.z, ww, az);
            aw = fmaf(v.w, ww, aw);
        }
    }
    ax += __shfl_xor(ax, 16); ax += __shfl_xor(ax, 32);
    ay += __shfl_xor(ay, 16); ay += __shfl_xor(ay, 32);
    az += __shfl_xor(az, 16); az += __shfl_xor(az, 32);
    aw += __shfl_xor(aw, 16); aw += __shfl_xor(aw, 32);
    if (g == 0) {
        float dd = dinv[wid];
        const float4 sv = *(const float4*)(t + (long long)wid * H + 4 * l);
        const float4 bv = *(const float4*)(b + 4 * l);
        float4 o;
        o.x = bv.x + dd * (ax + sv.x * dd);
        o.y = bv.y + dd * (ay + sv.y * dd);
        o.z = bv.z + dd * (az + sv.z * dd);
        o.w = bv.w + dd * (aw + sv.w * dd);
        *(float4*)(out + (long long)wid * H + 4 * l) = o;
    }
}

// ---------------- pooling: run-length segmented reduction (batch sorted) ----------------
constexpr int POOL_WAVES = 512;
constexpr int POOL_STRIP = (NN + POOL_WAVES - 1) / POOL_WAVES;  // 98

__global__ void k_pool(const float* __restrict__ h, const int* __restrict__ batch,
                       float* __restrict__ sums, float* __restrict__ cnt) {
    int wid = (blockIdx.x * blockDim.x + threadIdx.x) >> 6;
    int c = threadIdx.x & 63;
    int beg = wid * POOL_STRIP, end = min(NN, beg + POOL_STRIP);
    if (beg >= end) return;
    int curg = batch[beg];
    float acc = 0.0f; int run = 0;
    for (int r = beg; r < end; ++r) {
        int g = batch[r];
        if (g != curg) {
            atomicAdd(&sums[curg * H + c], acc);
            if (c == 0) atomicAdd(&cnt[curg], (float)run);
            curg = g; acc = 0.0f; run = 0;
        }
        acc += h[(long long)r * H + c];
        ++run;
    }
    atomicAdd(&sums[curg * H + c], acc);
    if (c == 0) atomicAdd(&cnt[curg], (float)run);
}

// ---------------- head ----------------
__global__ void k_head(const float* __restrict__ sums, const float* __restrict__ cnt,
                       const float* __restrict__ Wpre, const float* __restrict__ bpre,
                       const float* __restrict__ Wlin, const float* __restrict__ blin,
                       float* __restrict__ out) {
    __shared__ float g[NG * H];
    __shared__ float p[NG * 32];
    int tid = threadIdx.x;
    for (int i = tid; i < NG * H; i += blockDim.x) {
        int gi = i >> 6;
        g[i] = sums[i] / fmaxf(cnt[gi], 1.0f);
    }
    __syncthreads();
    for (int i = tid; i < NG * 32; i += blockDim.x) {
        int gi = i >> 5, j = i & 31;
        float acc = bpre[j];
        for (int k = 0; k < H; ++k) acc = fmaf(g[gi * H + k], Wpre[k * 32 + j], acc);
        p[i] = acc;
    }
    __syncthreads();
    for (int i = tid; i < NG * 4; i += blockDim.x) {
        int gi = i >> 2, o = i & 3;
        float acc = blin[o];
        for (int j = 0; j < 32; ++j) acc = fmaf(p[gi * 32 + j], Wlin[j * 4 + o], acc);
        out[i] = acc;
    }
}

extern "C" void kernel_launch(void* const* d_in, const int* in_sizes, int n_in,
                              void* d_out, int out_size, void* d_ws, size_t ws_size,
                              hipStream_t stream) {
    const float* x     = (const float*)d_in[0];
    const int*   ei    = (const int*)d_in[1];
    const int*   batch = (const int*)d_in[2];
    const float* W1    = (const float*)d_in[3];
    const float* b1    = (const float*)d_in[4];
    const float* W2    = (const float*)d_in[5];
    const float* b2    = (const float*)d_in[6];
    const float* W3    = (const float*)d_in[7];
    const float* b3    = (const float*)d_in[8];
    const float* Wpre  = (const float*)d_in[9];
    const float* bpre  = (const float*)d_in[10];
    const float* Wlin  = (const float*)d_in[11];
    const float* blin  = (const float*)d_in[12];
    float* out = (float*)d_out;

    const int* src = ei;
    const int* dst = ei + NE;

    // workspace layout
    int*   degi   = (int*)d_ws;            // NN
    float* sums   = (float*)(degi + NN);   // NG*H
    float* cnt    = sums + NG * H;         // NG
    int*   bsum   = (int*)(cnt + NG);      // SCAN_NB
    int*   rowptr = bsum + SCAN_NB;        // NN
    int*   csr_s  = rowptr + NN;           // NE
    float* dinv   = (float*)(csr_s + NE);  // NN
    float* tbuf   = dinv + NN;             // NN*H
    float* hA     = tbuf + (long long)NN * H;
    float* hB     = hA + (long long)NN * H;

    const int B = 256;
    const int gE  = (NE + B - 1) / B;
    const int gNH = (NN * H + B - 1) / B;     // one wave per node (conv)
    const int gG  = (NN + 63) / 64;           // gemm: 64 rows per block

    // zero degi/sums/cnt with our own kernel (runtime memset is ~45 us!)
    k_zero<<<(NN + NG * H + NG + B - 1) / B, B, 0, stream>>>(degi, sums, cnt);

    // CSR + norm
    k_degi<<<gE, B, 0, stream>>>(dst, degi);
    k_scanA<<<SCAN_NB, SCAN_B, 0, stream>>>(degi, rowptr, bsum);
    k_scanB<<<1, 64, 0, stream>>>(bsum);
    k_scanC<<<SCAN_NB, SCAN_B, 0, stream>>>(bsum, rowptr, degi, dinv);
    k_fill<<<gE, B, 0, stream>>>(src, dst, rowptr, csr_s);

    // conv1
    k_gemm<4, false><<<gG, B, 0, stream>>>(x, W1, tbuf);
    k_conv<<<gNH, B, 0, stream>>>(tbuf, rowptr, csr_s, dinv, b1, hA);
    // conv2
    k_gemm<H, true><<<gG, B, 0, stream>>>(hA, W2, tbuf);
    k_conv<<<gNH, B, 0, stream>>>(tbuf, rowptr, csr_s, dinv, b2, hB);
    // conv3
    k_gemm<H, true><<<gG, B, 0, stream>>>(hB, W3, tbuf);
    k_conv<<<gNH, B, 0, stream>>>(tbuf, rowptr, csr_s, dinv, b3, hA);

    // pool + head
    k_pool<<<POOL_WAVES / 4, B, 0, stream>>>(hA, batch, sums, cnt);
    k_head<<<1, B, 0, stream>>>(sums, cnt, Wpre, bpre, Wlin, blin, out);
}

// Round 6
// 281.036 us; speedup vs baseline: 1.1410x; 1.1410x over previous
//
#include <hip/hip_runtime.h>

constexpr int NN = 50000;   // nodes
constexpr int NE = 800000;  // edges
constexpr int H  = 64;      // hidden
constexpr int NG = 64;      // graphs

constexpr int SCAN_B  = 1024;
constexpr int SCAN_NB = (NN + SCAN_B - 1) / SCAN_B;  // 49

// ---------------- zero scratch ----------------
__global__ void k_zero(int* __restrict__ degi, float* __restrict__ sums,
                       float* __restrict__ cnt) {
    int i = blockIdx.x * blockDim.x + threadIdx.x;
    const int total = NN + NG * H + NG;
    for (; i < total; i += gridDim.x * blockDim.x) {
        if (i < NN) degi[i] = 0;
        else if (i < NN + NG * H) sums[i - NN] = 0.0f;
        else cnt[i - NN - NG * H] = 0.0f;
    }
}

// ---------------- CSR build (XCD-range partitioned) ----------------
// block bid handles only dst in range (bid & 7); with default round-robin
// block->XCD dispatch, each range's target window stays in one XCD's L2.
constexpr int RB = 2048;  // total blocks (256 per range)

__global__ void k_degi(const int* __restrict__ dst, int* __restrict__ degi) {
    int range = blockIdx.x & 7;
    int lo = range * (NN / 8), hi = (range == 7) ? NN : lo + NN / 8;
    int stride = (gridDim.x >> 3) * blockDim.x;
    for (int e = (blockIdx.x >> 3) * blockDim.x + threadIdx.x; e < NE; e += stride) {
        int d = dst[e];
        if (d >= lo && d < hi) atomicAdd(&degi[d], 1);
    }
}

// per-block local exclusive scan; bsum[b] = block total
__global__ void k_scanA(const int* __restrict__ degi, int* __restrict__ rowptr,
                        int* __restrict__ bsum) {
    int tid = threadIdx.x, b = blockIdx.x;
    int i = b * SCAN_B + tid;
    int d = (i < NN) ? degi[i] : 0;
    int lane = tid & 63, w = tid >> 6;
    int v = d;
    for (int off = 1; off < 64; off <<= 1) {
        int u = __shfl_up(v, off);
        if (lane >= off) v += u;
    }
    __shared__ int wt[16], wo[16];
    if (lane == 63) wt[w] = v;
    __syncthreads();
    if (tid == 0) {
        int a = 0;
        for (int k = 0; k < 16; ++k) { wo[k] = a; a += wt[k]; }
        bsum[b] = a;
    }
    __syncthreads();
    if (i < NN) rowptr[i] = v - d + wo[w];
}

__global__ void k_scanB(int* __restrict__ bsum) {
    int lane = threadIdx.x;
    int v = (lane < SCAN_NB) ? bsum[lane] : 0;
    int s = v;
    for (int off = 1; off < 64; off <<= 1) {
        int u = __shfl_up(s, off);
        if (lane >= off) s += u;
    }
    if (lane < SCAN_NB) bsum[lane] = s - v;
}

__global__ void k_scanC(const int* __restrict__ bsum, int* __restrict__ rowptr,
                        const int* __restrict__ degi, float* __restrict__ dinv) {
    int i = blockIdx.x * SCAN_B + threadIdx.x;
    if (i < NN) {
        rowptr[i] += bsum[blockIdx.x];
        dinv[i] = rsqrtf((float)(degi[i] + 1));  // +1 self-loop
    }
}

// fill via pos = atomicAdd(&rowptr[d],1); post-fill rowptr[d] == segment end.
__global__ void k_fill(const int* __restrict__ src, const int* __restrict__ dst,
                       int* __restrict__ rowptr, int* __restrict__ csr_src) {
    int range = blockIdx.x & 7;
    int lo = range * (NN / 8), hi = (range == 7) ? NN : lo + NN / 8;
    int stride = (gridDim.x >> 3) * blockDim.x;
    for (int e = (blockIdx.x >> 3) * blockDim.x + threadIdx.x; e < NE; e += stride) {
        int d = dst[e];
        if (d >= lo && d < hi) {
            int pos = atomicAdd(&rowptr[d], 1);
            csr_src[pos] = src[e];
        }
    }
}

// ---------------- conv1 aggregation on raw X (N x 4): Y = A_hat * X ----------------
// wave per dst; lane = (g = lane>>2 edge group of 16, c = lane&3 channel)
__global__ void k_aggX(const float* __restrict__ X, const int* __restrict__ rowptr,
                       const int* __restrict__ csr_src, const float* __restrict__ dinv,
                       float* __restrict__ Y) {
    int wid = (blockIdx.x * blockDim.x + threadIdx.x) >> 6;
    int lane = threadIdx.x & 63;
    int c = lane & 3, g = lane >> 2;
    if (wid >= NN) return;
    int beg = (wid > 0) ? rowptr[wid - 1] : 0;
    int end = rowptr[wid];
    float acc = 0.0f;
    for (int k = beg + g; k < end; k += 16) {
        int s = csr_src[k];
        acc = fmaf(X[(long long)s * 4 + c], dinv[s], acc);
    }
    acc += __shfl_xor(acc, 4);
    acc += __shfl_xor(acc, 8);
    acc += __shfl_xor(acc, 16);
    acc += __shfl_xor(acc, 32);
    if (g == 0) {
        float dd = dinv[wid];
        Y[(long long)wid * 4 + c] = dd * (acc + X[(long long)wid * 4 + c] * dd);
    }
}

// ---------------- dense per-node GEMM: t = act(h) @ W (+ bias) ----------------
// block = 256 threads; each thread computes a 4-row x 4-channel micro-tile.
template <int K, bool RELU, bool BIAS>
__global__ void k_gemm(const float* __restrict__ h, const float* __restrict__ W,
                       const float* __restrict__ bias, float* __restrict__ t) {
    __shared__ float4 Wl[K][16];
    int tid = threadIdx.x;
    {
        const float4* W4 = (const float4*)W;
        for (int i = tid; i < K * 16; i += 256) ((float4*)Wl)[i] = W4[i];
    }
    __syncthreads();
    int cg = tid & 15;
    int rg = tid >> 4;
    int row0 = blockIdx.x * 64 + rg * 4;

    float4 binit = make_float4(0.f, 0.f, 0.f, 0.f);
    if (BIAS) binit = ((const float4*)bias)[cg];
    float4 acc[4];
#pragma unroll
    for (int i = 0; i < 4; ++i) acc[i] = binit;

    const float4* h4 = (const float4*)h;
#pragma unroll
    for (int k4 = 0; k4 < K / 4; ++k4) {
        float4 w0 = Wl[4 * k4 + 0][cg];
        float4 w1 = Wl[4 * k4 + 1][cg];
        float4 w2 = Wl[4 * k4 + 2][cg];
        float4 w3 = Wl[4 * k4 + 3][cg];
#pragma unroll
        for (int i = 0; i < 4; ++i) {
            int r = row0 + i;
            if (r >= NN) break;
            float4 hv = h4[(long long)r * (K / 4) + k4];
            if (RELU) {
                hv.x = fmaxf(hv.x, 0.f); hv.y = fmaxf(hv.y, 0.f);
                hv.z = fmaxf(hv.z, 0.f); hv.w = fmaxf(hv.w, 0.f);
            }
            acc[i].x = fmaf(hv.x, w0.x, acc[i].x);
            acc[i].y = fmaf(hv.x, w0.y, acc[i].y);
            acc[i].z = fmaf(hv.x, w0.z, acc[i].z);
            acc[i].w = fmaf(hv.x, w0.w, acc[i].w);
            acc[i].x = fmaf(hv.y, w1.x, acc[i].x);
            acc[i].y = fmaf(hv.y, w1.y, acc[i].y);
            acc[i].z = fmaf(hv.y, w1.z, acc[i].z);
            acc[i].w = fmaf(hv.y, w1.w, acc[i].w);
            acc[i].x = fmaf(hv.z, w2.x, acc[i].x);
            acc[i].y = fmaf(hv.z, w2.y, acc[i].y);
            acc[i].z = fmaf(hv.z, w2.z, acc[i].z);
            acc[i].w = fmaf(hv.z, w2.w, acc[i].w);
            acc[i].x = fmaf(hv.w, w3.x, acc[i].x);
            acc[i].y = fmaf(hv.w, w3.y, acc[i].y);
            acc[i].z = fmaf(hv.w, w3.z, acc[i].z);
            acc[i].w = fmaf(hv.w, w3.w, acc[i].w);
        }
    }
#pragma unroll
    for (int i = 0; i < 4; ++i) {
        int r = row0 + i;
        if (r < NN) *(float4*)(t + (long long)r * H + 4 * cg) = acc[i];
    }
}

// ---------------- pull conv (H=64) ----------------
// out[d] = b + dinv[d]*( sum_s t[s]*dinv[s] + t[d]*dinv[d] )
__global__ void k_conv(const float* __restrict__ t, const int* __restrict__ rowptr,
                       const int* __restrict__ csr_src, const float* __restrict__ dinv,
                       const float* __restrict__ b, float* __restrict__ out) {
    int wid = (blockIdx.x * blockDim.x + threadIdx.x) >> 6;
    int lane = threadIdx.x & 63;
    int l = lane & 15, g = lane >> 4;
    if (wid >= NN) return;
    float ax = 0.0f, ay = 0.0f, az = 0.0f, aw = 0.0f;
    int beg = (wid > 0) ? rowptr[wid - 1] : 0;
    int end = rowptr[wid];
    for (int base = beg; base < end; base += 64) {
        int k = base + lane;
        int s = 0; float w = 0.0f;
        if (k < end) { s = csr_src[k]; w = dinv[s]; }
        int n = end - base; if (n > 64) n = 64;
        int iters = (n + 3) >> 2;
        for (int j = 0; j < iters; ++j) {
            int idx = 4 * j + g;
            int ss = __shfl(s, idx);
            float ww = __shfl(w, idx);
            const float4 v = *(const float4*)(t + (long long)ss * H + 4 * l);
            ax = fmaf(v.x, ww, ax);
            ay = fmaf(v.y, ww, ay);
            az = fmaf(v.z, ww, az);
            aw = fmaf(v.w, ww, aw);
        }
    }
    ax += __shfl_xor(ax, 16); ax += __shfl_xor(ax, 32);
    ay += __shfl_xor(ay, 16); ay += __shfl_xor(ay, 32);
    az += __shfl_xor(az, 16); az += __shfl_xor(az, 32);
    aw += __shfl_xor(aw, 16); aw += __shfl_xor(aw, 32);
    if (g == 0) {
        float dd = dinv[wid];
        const float4 sv = *(const float4*)(t + (long long)wid * H + 4 * l);
        const float4 bv = *(const float4*)(b + 4 * l);
        float4 o;
        o.x = bv.x + dd * (ax + sv.x * dd);
        o.y = bv.y + dd * (ay + sv.y * dd);
        o.z = bv.z + dd * (az + sv.z * dd);
        o.w = bv.w + dd * (aw + sv.w * dd);
        *(float4*)(out + (long long)wid * H + 4 * l) = o;
    }
}

// ---------------- pooling (batch sorted) ----------------
constexpr int POOL_WAVES = 512;
constexpr int POOL_STRIP = (NN + POOL_WAVES - 1) / POOL_WAVES;  // 98

__global__ void k_pool(const float* __restrict__ h, const int* __restrict__ batch,
                       float* __restrict__ sums, float* __restrict__ cnt) {
    int wid = (blockIdx.x * blockDim.x + threadIdx.x) >> 6;
    int c = threadIdx.x & 63;
    int beg = wid * POOL_STRIP, end = min(NN, beg + POOL_STRIP);
    if (beg >= end) return;
    int curg = batch[beg];
    float acc = 0.0f; int run = 0;
    for (int r = beg; r < end; ++r) {
        int g = batch[r];
        if (g != curg) {
            atomicAdd(&sums[curg * H + c], acc);
            if (c == 0) atomicAdd(&cnt[curg], (float)run);
            curg = g; acc = 0.0f; run = 0;
        }
        acc += h[(long long)r * H + c];
        ++run;
    }
    atomicAdd(&sums[curg * H + c], acc);
    if (c == 0) atomicAdd(&cnt[curg], (float)run);
}

// ---------------- head ----------------
__global__ void k_head(const float* __restrict__ sums, const float* __restrict__ cnt,
                       const float* __restrict__ Wpre, const float* __restrict__ bpre,
                       const float* __restrict__ Wlin, const float* __restrict__ blin,
                       float* __restrict__ out) {
    __shared__ float g[NG * H];
    __shared__ float p[NG * 32];
    int tid = threadIdx.x;
    for (int i = tid; i < NG * H; i += blockDim.x) {
        int gi = i >> 6;
        g[i] = sums[i] / fmaxf(cnt[gi], 1.0f);
    }
    __syncthreads();
    for (int i = tid; i < NG * 32; i += blockDim.x) {
        int gi = i >> 5, j = i & 31;
        float acc = bpre[j];
        for (int k = 0; k < H; ++k) acc = fmaf(g[gi * H + k], Wpre[k * 32 + j], acc);
        p[i] = acc;
    }
    __syncthreads();
    for (int i = tid; i < NG * 4; i += blockDim.x) {
        int gi = i >> 2, o = i & 3;
        float acc = blin[o];
        for (int j = 0; j < 32; ++j) acc = fmaf(p[gi * 32 + j], Wlin[j * 4 + o], acc);
        out[i] = acc;
    }
}

extern "C" void kernel_launch(void* const* d_in, const int* in_sizes, int n_in,
                              void* d_out, int out_size, void* d_ws, size_t ws_size,
                              hipStream_t stream) {
    const float* x     = (const float*)d_in[0];
    const int*   ei    = (const int*)d_in[1];
    const int*   batch = (const int*)d_in[2];
    const float* W1    = (const float*)d_in[3];
    const float* b1    = (const float*)d_in[4];
    const float* W2    = (const float*)d_in[5];
    const float* b2    = (const float*)d_in[6];
    const float* W3    = (const float*)d_in[7];
    const float* b3    = (const float*)d_in[8];
    const float* Wpre  = (const float*)d_in[9];
    const float* bpre  = (const float*)d_in[10];
    const float* Wlin  = (const float*)d_in[11];
    const float* blin  = (const float*)d_in[12];
    float* out = (float*)d_out;

    const int* src = ei;
    const int* dst = ei + NE;

    // workspace layout
    int*   degi   = (int*)d_ws;            // NN
    float* sums   = (float*)(degi + NN);   // NG*H
    float* cnt    = sums + NG * H;         // NG
    int*   bsum   = (int*)(cnt + NG);      // SCAN_NB
    int*   rowptr = bsum + SCAN_NB;        // NN
    int*   csr_s  = rowptr + NN;           // NE
    float* dinv   = (float*)(csr_s + NE);  // NN
    float* ybuf   = dinv + NN;             // NN*4
    float* tbuf   = ybuf + (long long)NN * 4;  // NN*H
    float* hA     = tbuf + (long long)NN * H;
    float* hB     = hA + (long long)NN * H;

    const int B = 256;
    const int gNH = (NN * H + B - 1) / B;     // one wave per node
    const int gG  = (NN + 63) / 64;           // gemm: 64 rows per block

    k_zero<<<(NN + NG * H + NG + B - 1) / B, B, 0, stream>>>(degi, sums, cnt);

    // CSR + norm (XCD-range partitioned build)
    k_degi<<<RB, B, 0, stream>>>(dst, degi);
    k_scanA<<<SCAN_NB, SCAN_B, 0, stream>>>(degi, rowptr, bsum);
    k_scanB<<<1, 64, 0, stream>>>(bsum);
    k_scanC<<<SCAN_NB, SCAN_B, 0, stream>>>(bsum, rowptr, degi, dinv);
    k_fill<<<RB, B, 0, stream>>>(src, dst, rowptr, csr_s);

    // conv1 reassociated: Y = A_hat * X, then hA = Y @ W1 + b1
    k_aggX<<<gNH, B, 0, stream>>>(x, rowptr, csr_s, dinv, ybuf);
    k_gemm<4, false, true><<<gG, B, 0, stream>>>(ybuf, W1, b1, hA);

    // conv2
    k_gemm<H, true, false><<<gG, B, 0, stream>>>(hA, W2, nullptr, tbuf);
    k_conv<<<gNH, B, 0, stream>>>(tbuf, rowptr, csr_s, dinv, b2, hB);
    // conv3
    k_gemm<H, true, false><<<gG, B, 0, stream>>>(hB, W3, nullptr, tbuf);
    k_conv<<<gNH, B, 0, stream>>>(tbuf, rowptr, csr_s, dinv, b3, hA);

    // pool + head
    k_pool<<<POOL_WAVES / 4, B, 0, stream>>>(hA, batch, sums, cnt);
    k_head<<<1, B, 0, stream>>>(sums, cnt, Wpre, bpre, Wlin, blin, out);
}

// Round 7
// 275.309 us; speedup vs baseline: 1.1647x; 1.0208x over previous
//
#include <hip/hip_runtime.h>

constexpr int NN = 50000;   // nodes
constexpr int NE = 800000;  // edges
constexpr int H  = 64;      // hidden
constexpr int NG = 64;      // graphs

constexpr int SCAN_B  = 1024;
constexpr int SCAN_NB = (NN + SCAN_B - 1) / SCAN_B;  // 49

// ---------------- zero degi ----------------
__global__ void k_zero(int* __restrict__ degi) {
    int i = blockIdx.x * blockDim.x + threadIdx.x;
    if (i < NN) degi[i] = 0;
}

// ---------------- CSR build (XCD-range partitioned) ----------------
// block bid handles only dst in range (bid & 7); with default round-robin
// block->XCD dispatch, each range's target window stays in one XCD's L2.
constexpr int RB = 2048;  // total blocks (256 per range)

__global__ void k_degi(const int* __restrict__ dst, int* __restrict__ degi) {
    int range = blockIdx.x & 7;
    int lo = range * (NN / 8), hi = (range == 7) ? NN : lo + NN / 8;
    int stride = (gridDim.x >> 3) * blockDim.x;
    for (int e = (blockIdx.x >> 3) * blockDim.x + threadIdx.x; e < NE; e += stride) {
        int d = dst[e];
        if (d >= lo && d < hi) atomicAdd(&degi[d], 1);
    }
}

// per-block local exclusive scan; bsum[b] = block total; also zeros sums/cnt
__global__ void k_scanA(const int* __restrict__ degi, int* __restrict__ rowptr,
                        int* __restrict__ bsum, float* __restrict__ sums,
                        float* __restrict__ cnt) {
    int tid = threadIdx.x, b = blockIdx.x;
    // fold pool-scratch zeroing into this pass (block 0..4 covers NG*H+NG)
    int zi = b * SCAN_B + tid;
    if (zi < NG * H) sums[zi] = 0.0f;
    else if (zi < NG * H + NG) cnt[zi - NG * H] = 0.0f;

    int i = b * SCAN_B + tid;
    int d = (i < NN) ? degi[i] : 0;
    int lane = tid & 63, w = tid >> 6;
    int v = d;
    for (int off = 1; off < 64; off <<= 1) {
        int u = __shfl_up(v, off);
        if (lane >= off) v += u;
    }
    __shared__ int wt[16], wo[16];
    if (lane == 63) wt[w] = v;
    __syncthreads();
    if (tid == 0) {
        int a = 0;
        for (int k = 0; k < 16; ++k) { wo[k] = a; a += wt[k]; }
        bsum[b] = a;
    }
    __syncthreads();
    if (i < NN) rowptr[i] = v - d + wo[w];
}

__global__ void k_scanB(int* __restrict__ bsum) {
    int lane = threadIdx.x;
    int v = (lane < SCAN_NB) ? bsum[lane] : 0;
    int s = v;
    for (int off = 1; off < 64; off <<= 1) {
        int u = __shfl_up(s, off);
        if (lane >= off) s += u;
    }
    if (lane < SCAN_NB) bsum[lane] = s - v;
}

__global__ void k_scanC(const int* __restrict__ bsum, int* __restrict__ rowptr,
                        const int* __restrict__ degi, float* __restrict__ dinv) {
    int i = blockIdx.x * SCAN_B + threadIdx.x;
    if (i < NN) {
        rowptr[i] += bsum[blockIdx.x];
        dinv[i] = rsqrtf((float)(degi[i] + 1));  // +1 self-loop
    }
}

// fill via pos = atomicAdd(&rowptr[d],1); post-fill rowptr[d] == segment end.
__global__ void k_fill(const int* __restrict__ src, const int* __restrict__ dst,
                       int* __restrict__ rowptr, int* __restrict__ csr_src) {
    int range = blockIdx.x & 7;
    int lo = range * (NN / 8), hi = (range == 7) ? NN : lo + NN / 8;
    int stride = (gridDim.x >> 3) * blockDim.x;
    for (int e = (blockIdx.x >> 3) * blockDim.x + threadIdx.x; e < NE; e += stride) {
        int d = dst[e];
        if (d >= lo && d < hi) {
            int pos = atomicAdd(&rowptr[d], 1);
            csr_src[pos] = src[e];
        }
    }
}

// ---------------- conv1 aggregation on raw X (N x 4): Y = A_hat * X ----------------
__global__ void k_aggX(const float* __restrict__ X, const int* __restrict__ rowptr,
                       const int* __restrict__ csr_src, const float* __restrict__ dinv,
                       float* __restrict__ Y) {
    int wid = (blockIdx.x * blockDim.x + threadIdx.x) >> 6;
    int lane = threadIdx.x & 63;
    int c = lane & 3, g = lane >> 2;
    if (wid >= NN) return;
    int beg = (wid > 0) ? rowptr[wid - 1] : 0;
    int end = rowptr[wid];
    float acc = 0.0f;
    for (int k = beg + g; k < end; k += 16) {
        int s = csr_src[k];
        acc = fmaf(X[(long long)s * 4 + c], dinv[s], acc);
    }
    acc += __shfl_xor(acc, 4);
    acc += __shfl_xor(acc, 8);
    acc += __shfl_xor(acc, 16);
    acc += __shfl_xor(acc, 32);
    if (g == 0) {
        float dd = dinv[wid];
        Y[(long long)wid * 4 + c] = dd * (acc + X[(long long)wid * 4 + c] * dd);
    }
}

// ---------------- dense per-node GEMM: t = act(h) @ W (+ bias) ----------------
template <int K, bool RELU, bool BIAS>
__global__ void k_gemm(const float* __restrict__ h, const float* __restrict__ W,
                       const float* __restrict__ bias, float* __restrict__ t) {
    __shared__ float4 Wl[K][16];
    int tid = threadIdx.x;
    {
        const float4* W4 = (const float4*)W;
        for (int i = tid; i < K * 16; i += 256) ((float4*)Wl)[i] = W4[i];
    }
    __syncthreads();
    int cg = tid & 15;
    int rg = tid >> 4;
    int row0 = blockIdx.x * 64 + rg * 4;

    float4 binit = make_float4(0.f, 0.f, 0.f, 0.f);
    if (BIAS) binit = ((const float4*)bias)[cg];
    float4 acc[4];
#pragma unroll
    for (int i = 0; i < 4; ++i) acc[i] = binit;

    const float4* h4 = (const float4*)h;
#pragma unroll
    for (int k4 = 0; k4 < K / 4; ++k4) {
        float4 w0 = Wl[4 * k4 + 0][cg];
        float4 w1 = Wl[4 * k4 + 1][cg];
        float4 w2 = Wl[4 * k4 + 2][cg];
        float4 w3 = Wl[4 * k4 + 3][cg];
#pragma unroll
        for (int i = 0; i < 4; ++i) {
            int r = row0 + i;
            if (r >= NN) break;
            float4 hv = h4[(long long)r * (K / 4) + k4];
            if (RELU) {
                hv.x = fmaxf(hv.x, 0.f); hv.y = fmaxf(hv.y, 0.f);
                hv.z = fmaxf(hv.z, 0.f); hv.w = fmaxf(hv.w, 0.f);
            }
            acc[i].x = fmaf(hv.x, w0.x, acc[i].x);
            acc[i].y = fmaf(hv.x, w0.y, acc[i].y);
            acc[i].z = fmaf(hv.x, w0.z, acc[i].z);
            acc[i].w = fmaf(hv.x, w0.w, acc[i].w);
            acc[i].x = fmaf(hv.y, w1.x, acc[i].x);
            acc[i].y = fmaf(hv.y, w1.y, acc[i].y);
            acc[i].z = fmaf(hv.y, w1.z, acc[i].z);
            acc[i].w = fmaf(hv.y, w1.w, acc[i].w);
            acc[i].x = fmaf(hv.z, w2.x, acc[i].x);
            acc[i].y = fmaf(hv.z, w2.y, acc[i].y);
            acc[i].z = fmaf(hv.z, w2.z, acc[i].z);
            acc[i].w = fmaf(hv.z, w2.w, acc[i].w);
            acc[i].x = fmaf(hv.w, w3.x, acc[i].x);
            acc[i].y = fmaf(hv.w, w3.y, acc[i].y);
            acc[i].z = fmaf(hv.w, w3.z, acc[i].z);
            acc[i].w = fmaf(hv.w, w3.w, acc[i].w);
        }
    }
#pragma unroll
    for (int i = 0; i < 4; ++i) {
        int r = row0 + i;
        if (r < NN) *(float4*)(t + (long long)r * H + 4 * cg) = acc[i];
    }
}

// ---------------- pull conv (H=64), 4-deep pipelined gathers ----------------
// out[d] = b + dinv[d]*( sum_s t[s]*dinv[s] + t[d]*dinv[d] )
// wave = 1 dst; lane = (g = lane>>4 edge group, l = lane&15 float4 slot).
// Per macro-iter: 16 edges — 8 shfl, 4 independent float4 loads, 16 fma4.
// OOB edge slots have w=0 (load row 0 harmlessly, contribute nothing).
__global__ void k_conv(const float* __restrict__ t, const int* __restrict__ rowptr,
                       const int* __restrict__ csr_src, const float* __restrict__ dinv,
                       const float* __restrict__ b, float* __restrict__ out) {
    int wid = (blockIdx.x * blockDim.x + threadIdx.x) >> 6;
    int lane = threadIdx.x & 63;
    int l = lane & 15, g = lane >> 4;
    if (wid >= NN) return;
    float ax = 0.0f, ay = 0.0f, az = 0.0f, aw = 0.0f;
    int beg = (wid > 0) ? rowptr[wid - 1] : 0;
    int end = rowptr[wid];
    for (int base = beg; base < end; base += 64) {
        int k = base + lane;
        int s = 0; float w = 0.0f;
        if (k < end) { s = csr_src[k]; w = dinv[s]; }
        int n = end - base; if (n > 64) n = 64;
        int rounds = (n + 15) >> 4;   // macro-iters of 16 edges
        for (int m = 0; m < rounds; ++m) {
            int j0 = 16 * m + g;
            int ss0 = __shfl(s, j0);      float ww0 = __shfl(w, j0);
            int ss1 = __shfl(s, j0 + 4);  float ww1 = __shfl(w, j0 + 4);
            int ss2 = __shfl(s, j0 + 8);  float ww2 = __shfl(w, j0 + 8);
            int ss3 = __shfl(s, j0 + 12); float ww3 = __shfl(w, j0 + 12);
            const float4 v0 = *(const float4*)(t + (long long)ss0 * H + 4 * l);
            const float4 v1 = *(const float4*)(t + (long long)ss1 * H + 4 * l);
            const float4 v2 = *(const float4*)(t + (long long)ss2 * H + 4 * l);
            const float4 v3 = *(const float4*)(t + (long long)ss3 * H + 4 * l);
            ax = fmaf(v0.x, ww0, ax); ay = fmaf(v0.y, ww0, ay);
            az = fmaf(v0.z, ww0, az); aw = fmaf(v0.w, ww0, aw);
            ax = fmaf(v1.x, ww1, ax); ay = fmaf(v1.y, ww1, ay);
            az = fmaf(v1.z, ww1, az); aw = fmaf(v1.w, ww1, aw);
            ax = fmaf(v2.x, ww2, ax); ay = fmaf(v2.y, ww2, ay);
            az = fmaf(v2.z, ww2, az); aw = fmaf(v2.w, ww2, aw);
            ax = fmaf(v3.x, ww3, ax); ay = fmaf(v3.y, ww3, ay);
            az = fmaf(v3.z, ww3, az); aw = fmaf(v3.w, ww3, aw);
        }
    }
    ax += __shfl_xor(ax, 16); ax += __shfl_xor(ax, 32);
    ay += __shfl_xor(ay, 16); ay += __shfl_xor(ay, 32);
    az += __shfl_xor(az, 16); az += __shfl_xor(az, 32);
    aw += __shfl_xor(aw, 16); aw += __shfl_xor(aw, 32);
    if (g == 0) {
        float dd = dinv[wid];
        const float4 sv = *(const float4*)(t + (long long)wid * H + 4 * l);
        const float4 bv = *(const float4*)(b + 4 * l);
        float4 o;
        o.x = bv.x + dd * (ax + sv.x * dd);
        o.y = bv.y + dd * (ay + sv.y * dd);
        o.z = bv.z + dd * (az + sv.z * dd);
        o.w = bv.w + dd * (aw + sv.w * dd);
        *(float4*)(out + (long long)wid * H + 4 * l) = o;
    }
}

// ---------------- pooling (batch sorted) ----------------
constexpr int POOL_WAVES = 512;
constexpr int POOL_STRIP = (NN + POOL_WAVES - 1) / POOL_WAVES;  // 98

__global__ void k_pool(const float* __restrict__ h, const int* __restrict__ batch,
                       float* __restrict__ sums, float* __restrict__ cnt) {
    int wid = (blockIdx.x * blockDim.x + threadIdx.x) >> 6;
    int c = threadIdx.x & 63;
    int beg = wid * POOL_STRIP, end = min(NN, beg + POOL_STRIP);
    if (beg >= end) return;
    int curg = batch[beg];
    float acc = 0.0f; int run = 0;
    for (int r = beg; r < end; ++r) {
        int g = batch[r];
        if (g != curg) {
            atomicAdd(&sums[curg * H + c], acc);
            if (c == 0) atomicAdd(&cnt[curg], (float)run);
            curg = g; acc = 0.0f; run = 0;
        }
        acc += h[(long long)r * H + c];
        ++run;
    }
    atomicAdd(&sums[curg * H + c], acc);
    if (c == 0) atomicAdd(&cnt[curg], (float)run);
}

// ---------------- head ----------------
__global__ void k_head(const float* __restrict__ sums, const float* __restrict__ cnt,
                       const float* __restrict__ Wpre, const float* __restrict__ bpre,
                       const float* __restrict__ Wlin, const float* __restrict__ blin,
                       float* __restrict__ out) {
    __shared__ float g[NG * H];
    __shared__ float p[NG * 32];
    int tid = threadIdx.x;
    for (int i = tid; i < NG * H; i += blockDim.x) {
        int gi = i >> 6;
        g[i] = sums[i] / fmaxf(cnt[gi], 1.0f);
    }
    __syncthreads();
    for (int i = tid; i < NG * 32; i += blockDim.x) {
        int gi = i >> 5, j = i & 31;
        float acc = bpre[j];
        for (int k = 0; k < H; ++k) acc = fmaf(g[gi * H + k], Wpre[k * 32 + j], acc);
        p[i] = acc;
    }
    __syncthreads();
    for (int i = tid; i < NG * 4; i += blockDim.x) {
        int gi = i >> 2, o = i & 3;
        float acc = blin[o];
        for (int j = 0; j < 32; ++j) acc = fmaf(p[gi * 32 + j], Wlin[j * 4 + o], acc);
        out[i] = acc;
    }
}

extern "C" void kernel_launch(void* const* d_in, const int* in_sizes, int n_in,
                              void* d_out, int out_size, void* d_ws, size_t ws_size,
                              hipStream_t stream) {
    const float* x     = (const float*)d_in[0];
    const int*   ei    = (const int*)d_in[1];
    const int*   batch = (const int*)d_in[2];
    const float* W1    = (const float*)d_in[3];
    const float* b1    = (const float*)d_in[4];
    const float* W2    = (const float*)d_in[5];
    const float* b2    = (const float*)d_in[6];
    const float* W3    = (const float*)d_in[7];
    const float* b3    = (const float*)d_in[8];
    const float* Wpre  = (const float*)d_in[9];
    const float* bpre  = (const float*)d_in[10];
    const float* Wlin  = (const float*)d_in[11];
    const float* blin  = (const float*)d_in[12];
    float* out = (float*)d_out;

    const int* src = ei;
    const int* dst = ei + NE;

    // workspace layout
    int*   degi   = (int*)d_ws;            // NN
    float* sums   = (float*)(degi + NN);   // NG*H
    float* cnt    = sums + NG * H;         // NG
    int*   bsum   = (int*)(cnt + NG);      // SCAN_NB
    int*   rowptr = bsum + SCAN_NB;        // NN
    int*   csr_s  = rowptr + NN;           // NE
    float* dinv   = (float*)(csr_s + NE);  // NN
    float* ybuf   = dinv + NN;             // NN*4
    float* tbuf   = ybuf + (long long)NN * 4;  // NN*H
    float* hA     = tbuf + (long long)NN * H;
    float* hB     = hA + (long long)NN * H;

    const int B = 256;
    const int gNH = (NN * H + B - 1) / B;     // one wave per node
    const int gG  = (NN + 63) / 64;           // gemm: 64 rows per block

    k_zero<<<(NN + B - 1) / B, B, 0, stream>>>(degi);

    // CSR + norm (XCD-range partitioned build)
    k_degi<<<RB, B, 0, stream>>>(dst, degi);
    k_scanA<<<SCAN_NB, SCAN_B, 0, stream>>>(degi, rowptr, bsum, sums, cnt);
    k_scanB<<<1, 64, 0, stream>>>(bsum);
    k_scanC<<<SCAN_NB, SCAN_B, 0, stream>>>(bsum, rowptr, degi, dinv);
    k_fill<<<RB, B, 0, stream>>>(src, dst, rowptr, csr_s);

    // conv1 reassociated: Y = A_hat * X, then hA = Y @ W1 + b1
    k_aggX<<<gNH, B, 0, stream>>>(x, rowptr, csr_s, dinv, ybuf);
    k_gemm<4, false, true><<<gG, B, 0, stream>>>(ybuf, W1, b1, hA);

    // conv2
    k_gemm<H, true, false><<<gG, B, 0, stream>>>(hA, W2, nullptr, tbuf);
    k_conv<<<gNH, B, 0, stream>>>(tbuf, rowptr, csr_s, dinv, b2, hB);
    // conv3
    k_gemm<H, true, false><<<gG, B, 0, stream>>>(hB, W3, nullptr, tbuf);
    k_conv<<<gNH, B, 0, stream>>>(tbuf, rowptr, csr_s, dinv, b3, hA);

    // pool + head
    k_pool<<<POOL_WAVES / 4, B, 0, stream>>>(hA, batch, sums, cnt);
    k_head<<<1, B, 0, stream>>>(sums, cnt, Wpre, bpre, Wlin, blin, out);
}